// Round 2
// baseline (315.646 us; speedup 1.0000x reference)
//
#include <hip/hip_runtime.h>

// Problem: B=32, L=4, W=512, D=768, fp32.
// out = [word: B*D*W][sent: B*D]
//   word[b][d][s] = (1/L) * sum_{w: seg[b][w]==s} sum_l emb[b][l][w][d]
//   sent[b][d]    = (1/(W*L)) * sum_{w,l} emb[b][l][w][d]
//
// Single fused kernel. Block = (b, d-tile of 32). The block streams ALL 512
// words x 4 layers for its 32 d-columns, layer-sums in registers, and
// scatters into an LDS tile [32 d][513 s] via ds_add_f32 (segment axis lives
// in LDS -> no global atomics, no workspace, no transpose kernel). Unused
// segment columns stay zero from LDS init. Epilogue drains the tile as
// coalesced word[b][d][.] rows (already transposed) and writes sent locally.
//
// Geometry: LDS 32*513*4 = 65.7 KB -> 2 blocks/CU resident (160 KB LDS).
// Grid 32*24 = 768 blocks = exactly 3 per CU: balanced. 256 thr = 4 waves.

#define BB 32
#define LL 4
#define WW 512
#define DD 768
#define WORD_SIZE (BB * DD * WW)

#define DT   32              // d-columns per block
#define NDT  (DD / DT)       // 24 d-tiles
#define NTHR 256
#define TCOL 513             // padded segment axis (bank-conflict-free)
#define NIT  (WW / 32)       // 16 w-iterations per thread (32 phases)

__global__ __launch_bounds__(NTHR) void fused(
    const float* __restrict__ emb,   // [B, L, W, D]
    const int*   __restrict__ seg,   // [B, W], sorted, values in [0, W)
    float* __restrict__ word,        // [B, D, W]
    float* __restrict__ sent)        // [B, D]
{
    const int b   = blockIdx.x;
    const int d0  = blockIdx.y * DT;
    const int tid = threadIdx.x;

    __shared__ float tile[DT * TCOL];   // 65,664 B
    __shared__ float sentbuf[DT];
    __shared__ int   seg_sh[WW];

    // ---- init LDS ----
    for (int i = tid; i < DT * TCOL; i += NTHR) tile[i] = 0.f;
    if (tid < DT) sentbuf[tid] = 0.f;
    seg_sh[tid]        = seg[b * WW + tid];
    seg_sh[tid + NTHR] = seg[b * WW + tid + NTHR];
    __syncthreads();

    // ---- stream + scatter ----
    // thread: p = tid>>3 (w-phase, 0..31), di4 = tid&7 (float4 column, 0..7)
    const int p   = tid >> 3;
    const int di4 = tid & 7;
    const float4* e4 = (const float4*)emb;
    const size_t lstride = (size_t)WW * (DD / 4);
    const size_t base = (size_t)b * LL * WW * (DD / 4) + (size_t)(d0 / 4) + di4;

    float4 sacc = make_float4(0.f, 0.f, 0.f, 0.f);

#pragma unroll 4
    for (int it = 0; it < NIT; ++it) {
        const int w = it * 32 + p;
        const size_t off = base + (size_t)w * (DD / 4);
        float4 t0 = e4[off];
        float4 t1 = e4[off + lstride];
        float4 t2 = e4[off + 2 * lstride];
        float4 t3 = e4[off + 3 * lstride];
        float4 v;
        v.x = (t0.x + t1.x) + (t2.x + t3.x);
        v.y = (t0.y + t1.y) + (t2.y + t3.y);
        v.z = (t0.z + t1.z) + (t2.z + t3.z);
        v.w = (t0.w + t1.w) + (t2.w + t3.w);

        sacc.x += v.x; sacc.y += v.y; sacc.z += v.z; sacc.w += v.w;

        const int s = seg_sh[w];
        float* tp = &tile[(di4 * 4) * TCOL + s];
        atomicAdd(tp + 0 * TCOL, v.x);     // ds_add_f32; banks spread by row
        atomicAdd(tp + 1 * TCOL, v.y);
        atomicAdd(tp + 2 * TCOL, v.z);
        atomicAdd(tp + 3 * TCOL, v.w);
    }

    // sent partials (tiny: 4 LDS atomics per thread)
    atomicAdd(&sentbuf[di4 * 4 + 0], sacc.x);
    atomicAdd(&sentbuf[di4 * 4 + 1], sacc.y);
    atomicAdd(&sentbuf[di4 * 4 + 2], sacc.z);
    atomicAdd(&sentbuf[di4 * 4 + 3], sacc.w);
    __syncthreads();

    // ---- drain: tile -> word rows (coalesced, already transposed) ----
    const float q = 0.25f;                       // layer mean
    float* wout = word + ((size_t)b * DD + d0) * WW;
#pragma unroll
    for (int k = 0; k < (DT * WW) / NTHR; ++k) { // 64 scalar stores/thread
        const int flat = k * NTHR + tid;
        const int row  = flat >> 9;              // d-local
        const int col  = flat & 511;             // s
        wout[(size_t)row * WW + col] = tile[row * TCOL + col] * q;
    }
    if (tid < DT)
        sent[(size_t)b * DD + d0 + tid] = sentbuf[tid] * (1.0f / (WW * LL));
}

extern "C" void kernel_launch(void* const* d_in, const int* in_sizes, int n_in,
                              void* d_out, int out_size, void* d_ws, size_t ws_size,
                              hipStream_t stream) {
    const float* emb = (const float*)d_in[0];   // [32,4,512,768] fp32
    const int*   seg = (const int*)d_in[1];     // [32,512] int32, sorted per row
    float* out  = (float*)d_out;
    float* word = out;                          // [B, D, W]
    float* sent = out + WORD_SIZE;              // [B, D]
    (void)d_ws; (void)ws_size;                  // no workspace, no memset

    fused<<<dim3(BB, NDT), dim3(NTHR), 0, stream>>>(emb, seg, word, sent);
}